// Round 1
// baseline (307.219 us; speedup 1.0000x reference)
//
#include <hip/hip_runtime.h>

#define BB 256     // batch
#define E 512      // embed channels
#define HDE 512    // h dim
#define HW 256     // spatial (8*32)
#define CATT 512   // attention context channels
#define EC 8       // e-chunks for kernel A
#define ECH (E / EC)   // 64
#define SC 8       // s-chunks for kernel C
#define SCH (HW / SC)  // 32

// ws layout (floats):
//   scoresPart[EC][BB][HW]  : 8*256*256  = 524288 floats (2 MB)
//   outPart  [SC][BB][CATT] : 8*256*512  = 1048576 floats (4 MB)

__device__ __forceinline__ float fast_tanh(float x) {
    // tanh(x) = 1 - 2/(exp(2x)+1); saturates correctly for |x| large.
    float t = __expf(2.0f * x);
    return 1.0f - 2.0f / (t + 1.0f);
}

// ---------------- Kernel A: fused g-slice GEMM + tanh-weighted channel sum ----
// grid (BB, EC), block 256
__global__ __launch_bounds__(256, 4) void kA(
        const float* __restrict__ h, const float* __restrict__ x_em,
        const float* __restrict__ Wh, const float* __restrict__ bh,
        const float* __restrict__ Wa, float* __restrict__ scoresPart) {
    const int b = blockIdx.x;
    const int ec = blockIdx.y;
    const int t = threadIdx.x;

    __shared__ float sH[HDE];          // 2 KB, h row
    __shared__ float sG[ECH];          // g values for this e-chunk
    __shared__ float sWa[ECH];
    __shared__ float4 sPart[4][HW / 4]; // 4 KB

    // stage h[b,:]
    if (t < HDE / 4) {
        ((float4*)sH)[t] = ((const float4*)(h + (size_t)b * HDE))[t];
    }
    __syncthreads();

    // phase 1: g[e] for e_local = t>>2, split-K over ksub = t&3
    {
        const int el = t >> 2;
        const int ks = t & 3;
        const int e = ec * ECH + el;
        const float* wrow = Wh + (size_t)e * HDE;
        float acc = 0.0f;
#pragma unroll
        for (int i = 0; i < HDE / 16; ++i) {
            const int k = ks * 4 + i * 16;
            float4 w = *(const float4*)(wrow + k);
            float4 hv = *(const float4*)(sH + k);
            acc += w.x * hv.x + w.y * hv.y + w.z * hv.z + w.w * hv.w;
        }
        acc += __shfl_xor(acc, 1);
        acc += __shfl_xor(acc, 2);
        if (ks == 0) {
            sG[el] = acc + bh[e];
            sWa[el] = Wa[e];
        }
    }
    __syncthreads();

    // phase 2: stream x_em chunk, accumulate Wa[e]*tanh(x+g)
    const int s4 = t & 63;    // float4 index over s
    const int esub = t >> 6;  // 0..3 (one per wave)
    const float* xb = x_em + ((size_t)b * E + (size_t)ec * ECH) * HW + s4 * 4;
    float4 acc = {0.f, 0.f, 0.f, 0.f};
#pragma unroll 4
    for (int i = 0; i < ECH / 4; ++i) {
        const int el = 4 * i + esub;
        float4 x = *(const float4*)(xb + (size_t)el * HW);
        const float g = sG[el];
        const float wa = sWa[el];
        acc.x += wa * fast_tanh(x.x + g);
        acc.y += wa * fast_tanh(x.y + g);
        acc.z += wa * fast_tanh(x.z + g);
        acc.w += wa * fast_tanh(x.w + g);
    }

    // phase 3: reduce the 4 e-subgroups
    sPart[esub][s4] = acc;
    __syncthreads();
    if (t < HW / 4) {
        float4 r0 = sPart[0][t], r1 = sPart[1][t], r2 = sPart[2][t], r3 = sPart[3][t];
        float4 r;
        r.x = r0.x + r1.x + r2.x + r3.x;
        r.y = r0.y + r1.y + r2.y + r3.y;
        r.z = r0.z + r1.z + r2.z + r3.z;
        r.w = r0.w + r1.w + r2.w + r3.w;
        *(float4*)(scoresPart + ((size_t)ec * BB + b) * HW + t * 4) = r;
    }
}

// ---------------- Kernel B: reduce score partials + softmax -> alpha ---------
// grid (BB), block 256 (one thread per s)
__global__ __launch_bounds__(256, 4) void kB(
        const float* __restrict__ scoresPart, float* __restrict__ out) {
    const int b = blockIdx.x;
    const int t = threadIdx.x;
    float v = 0.0f;
#pragma unroll
    for (int ec = 0; ec < EC; ++ec)
        v += scoresPart[((size_t)ec * BB + b) * HW + t];

    __shared__ float sred[4];
    const int wid = t >> 6;

    float m = v;
#pragma unroll
    for (int o = 32; o; o >>= 1) m = fmaxf(m, __shfl_xor(m, o));
    if ((t & 63) == 0) sred[wid] = m;
    __syncthreads();
    m = fmaxf(fmaxf(sred[0], sred[1]), fmaxf(sred[2], sred[3]));
    __syncthreads();

    float p = __expf(v - m);
    float s = p;
#pragma unroll
    for (int o = 32; o; o >>= 1) s += __shfl_xor(s, o);
    if ((t & 63) == 0) sred[wid] = s;
    __syncthreads();
    s = sred[0] + sred[1] + sred[2] + sred[3];

    out[(size_t)BB * CATT + (size_t)b * HW + t] = p / s;
}

// ---------------- Kernel C: alpha-weighted sum of att_x_em (partials) --------
// grid (BB, SC), block 256
__global__ __launch_bounds__(256, 8) void kC(
        const float* __restrict__ att, const float* __restrict__ alpha,
        float* __restrict__ outPart) {
    const int b = blockIdx.x;
    const int sc = blockIdx.y;
    const int t = threadIdx.x;
    const int c4 = t & 127;   // float4 index over CATT
    const int sp = t >> 7;    // 2-way s split

    __shared__ float sA[SCH];
    __shared__ float4 sP[CATT / 4];

    if (t < SCH) sA[t] = alpha[(size_t)b * HW + sc * SCH + t];
    __syncthreads();

    const float* ab = att + ((size_t)b * HW + (size_t)sc * SCH) * CATT + c4 * 4;
    float4 acc = {0.f, 0.f, 0.f, 0.f};
#pragma unroll 4
    for (int i = 0; i < SCH / 2; ++i) {
        const int s = 2 * i + sp;
        float4 x = *(const float4*)(ab + (size_t)s * CATT);
        const float a = sA[s];
        acc.x += a * x.x;
        acc.y += a * x.y;
        acc.z += a * x.z;
        acc.w += a * x.w;
    }
    if (sp == 1) sP[c4] = acc;
    __syncthreads();
    if (sp == 0) {
        float4 o = sP[c4];
        acc.x += o.x; acc.y += o.y; acc.z += o.z; acc.w += o.w;
        *(float4*)(outPart + ((size_t)sc * BB + b) * CATT + c4 * 4) = acc;
    }
}

// ---------------- Kernel D: reduce out partials -> att_out -------------------
// grid (BB), block 128
__global__ __launch_bounds__(128, 8) void kD(
        const float* __restrict__ outPart, float* __restrict__ out) {
    const int b = blockIdx.x;
    const int t = threadIdx.x;
    float4 acc = {0.f, 0.f, 0.f, 0.f};
#pragma unroll
    for (int sc = 0; sc < SC; ++sc) {
        float4 x = *(const float4*)(outPart + ((size_t)sc * BB + b) * CATT + t * 4);
        acc.x += x.x; acc.y += x.y; acc.z += x.z; acc.w += x.w;
    }
    *(float4*)(out + (size_t)b * CATT + t * 4) = acc;
}

extern "C" void kernel_launch(void* const* d_in, const int* in_sizes, int n_in,
                              void* d_out, int out_size, void* d_ws, size_t ws_size,
                              hipStream_t stream) {
    const float* h      = (const float*)d_in[0];
    const float* x_em   = (const float*)d_in[1];
    const float* att    = (const float*)d_in[2];
    const float* Wh     = (const float*)d_in[3];
    const float* bh     = (const float*)d_in[4];
    const float* Wa     = (const float*)d_in[5];
    // d_in[6] = ba: softmax is shift-invariant and only alpha/att_out are
    // returned, so ba cancels exactly. d_in[7], d_in[8] = feature dims (fixed).

    float* out = (float*)d_out;                 // [BB*CATT] att_out, then [BB*HW] alpha
    float* scoresPart = (float*)d_ws;           // EC*BB*HW floats
    float* outPart = (float*)d_ws + (size_t)EC * BB * HW;  // SC*BB*CATT floats

    kA<<<dim3(BB, EC), 256, 0, stream>>>(h, x_em, Wh, bh, Wa, scoresPart);
    kB<<<dim3(BB), 256, 0, stream>>>(scoresPart, out);
    kC<<<dim3(BB, SC), 256, 0, stream>>>(att, out + (size_t)BB * CATT, outPart);
    kD<<<dim3(BB), 128, 0, stream>>>(outPart, out);
}